// Round 1
// baseline (429.298 us; speedup 1.0000x reference)
//
#include <hip/hip_runtime.h>

#define N_ROWS 32768
#define DIM 256
#define K_CODES 1024
#define OUT_QUANT 8388608  // N_ROWS*DIM; out layout: [quant | loss | encodings]

// ---------- exact numpy pairwise sum-of-squares over 128 contiguous floats ----------
__device__ __forceinline__ float pw128sq(const float* __restrict__ x) {
  float r[8];
#pragma unroll
  for (int j = 0; j < 8; ++j) r[j] = __fmul_rn(x[j], x[j]);
#pragma unroll
  for (int i = 8; i < 128; i += 8) {
#pragma unroll
    for (int j = 0; j < 8; ++j) r[j] = __fadd_rn(r[j], __fmul_rn(x[i + j], x[i + j]));
  }
  return __fadd_rn(__fadd_rn(__fadd_rn(r[0], r[1]), __fadd_rn(r[2], r[3])),
                   __fadd_rn(__fadd_rn(r[4], r[5]), __fadd_rn(r[6], r[7])));
}

__global__ __launch_bounds__(256) void row_norms(const float* __restrict__ z,
                                                 float* __restrict__ rn) {
  int r = blockIdx.x * 256 + threadIdx.x;
  if (r < N_ROWS)
    rn[r] = __fadd_rn(pw128sq(z + (size_t)r * DIM), pw128sq(z + (size_t)r * DIM + 128));
}

__global__ __launch_bounds__(256) void code_norms(const float* __restrict__ cb,
                                                  float* __restrict__ cn) {
  int k = blockIdx.x * 256 + threadIdx.x;
  if (k < K_CODES)
    cn[k] = __fadd_rn(pw128sq(cb + (size_t)k * DIM), pw128sq(cb + (size_t)k * DIM + 128));
}

// ---------- fused fp32 GEMM (z . cb^T) + per-row argmin of distances ----------
// block: 256 threads, tile 128 rows x 128 codes, thread tile 8x8, BK=16
__global__ __launch_bounds__(256) void gemm_argmin(
    const float* __restrict__ z, const float* __restrict__ cb,
    const float* __restrict__ rn, const float* __restrict__ cn,
    unsigned long long* __restrict__ keys) {
  __shared__ float As[16][132];
  __shared__ float Bs[16][132];
  __shared__ unsigned long long red[128];

  const int bm = blockIdx.x >> 3;
  const int bn = blockIdx.x & 7;
  const int row0 = bm * 128, col0 = bn * 128;
  const int tid = threadIdx.x;
  const int tx = tid & 15, ty = tid >> 4;
  const int lrow = tid >> 2;          // 0..63
  const int lc4 = (tid & 3) << 2;     // 0,4,8,12

  if (tid < 128) red[tid] = ~0ull;

  float acc[8][8];
#pragma unroll
  for (int i = 0; i < 8; ++i)
#pragma unroll
    for (int j = 0; j < 8; ++j) acc[i][j] = 0.f;

  for (int kk = 0; kk < DIM; kk += 16) {
    float4 a0 = *(const float4*)(z + (size_t)(row0 + lrow) * DIM + kk + lc4);
    float4 a1 = *(const float4*)(z + (size_t)(row0 + lrow + 64) * DIM + kk + lc4);
    float4 b0 = *(const float4*)(cb + (size_t)(col0 + lrow) * DIM + kk + lc4);
    float4 b1 = *(const float4*)(cb + (size_t)(col0 + lrow + 64) * DIM + kk + lc4);
    __syncthreads();
    As[lc4 + 0][lrow] = a0.x; As[lc4 + 1][lrow] = a0.y;
    As[lc4 + 2][lrow] = a0.z; As[lc4 + 3][lrow] = a0.w;
    As[lc4 + 0][lrow + 64] = a1.x; As[lc4 + 1][lrow + 64] = a1.y;
    As[lc4 + 2][lrow + 64] = a1.z; As[lc4 + 3][lrow + 64] = a1.w;
    Bs[lc4 + 0][lrow] = b0.x; Bs[lc4 + 1][lrow] = b0.y;
    Bs[lc4 + 2][lrow] = b0.z; Bs[lc4 + 3][lrow] = b0.w;
    Bs[lc4 + 0][lrow + 64] = b1.x; Bs[lc4 + 1][lrow + 64] = b1.y;
    Bs[lc4 + 2][lrow + 64] = b1.z; Bs[lc4 + 3][lrow + 64] = b1.w;
    __syncthreads();
#pragma unroll
    for (int k = 0; k < 16; ++k) {
      float av[8], bv[8];
      *(float4*)&av[0] = *(const float4*)&As[k][ty * 8];
      *(float4*)&av[4] = *(const float4*)&As[k][ty * 8 + 4];
      *(float4*)&bv[0] = *(const float4*)&Bs[k][tx * 4];
      *(float4*)&bv[4] = *(const float4*)&Bs[k][tx * 4 + 64];
#pragma unroll
      for (int i = 0; i < 8; ++i)
#pragma unroll
        for (int j = 0; j < 8; ++j) acc[i][j] = fmaf(av[i], bv[j], acc[i][j]);
    }
  }

  // epilogue: dist = fp32((rownorm + codenorm) - 2*dot), argmin with first-index ties
#pragma unroll
  for (int i = 0; i < 8; ++i) {
    const int m = ty * 8 + i;
    const float a = rn[row0 + m];
    unsigned long long best = ~0ull;
#pragma unroll
    for (int j = 0; j < 8; ++j) {
      const int c = col0 + ((j < 4) ? (tx * 4 + j) : (64 + tx * 4 + (j - 4)));
      const float d = __fsub_rn(__fadd_rn(a, cn[c]), 2.0f * acc[i][j]);
      unsigned int b = __float_as_uint(d);
      b = (b & 0x80000000u) ? ~b : (b | 0x80000000u);
      const unsigned long long key = ((unsigned long long)b << 32) | (unsigned int)c;
      if (key < best) best = key;
    }
    atomicMin(&red[m], best);
  }
  __syncthreads();
  if (tid < 128) atomicMin(&keys[row0 + tid], red[tid]);
}

// ---------- outputs: quantized (straight-through replicated), one-hot, loss partials ----------
__global__ __launch_bounds__(256) void quantize_out(
    const float* __restrict__ z, const float* __restrict__ cb,
    const unsigned long long* __restrict__ keys,
    float* __restrict__ out, float* __restrict__ lossp) {
  __shared__ float ls[4];
  const int wid = threadIdx.x >> 6, lane = threadIdx.x & 63;
  const int row = blockIdx.x * 4 + wid;
  const int idx = (int)(keys[row] & 0xffffffffull);
  const float4 zv = *(const float4*)(z + (size_t)row * DIM + lane * 4);
  const float4 qv = *(const float4*)(cb + (size_t)idx * DIM + lane * 4);
  const float dx = __fsub_rn(qv.x, zv.x);
  const float dy = __fsub_rn(qv.y, zv.y);
  const float dzz = __fsub_rn(qv.z, zv.z);
  const float dw = __fsub_rn(qv.w, zv.w);
  float4 ov;
  ov.x = __fadd_rn(zv.x, dx); ov.y = __fadd_rn(zv.y, dy);
  ov.z = __fadd_rn(zv.z, dzz); ov.w = __fadd_rn(zv.w, dw);
  *(float4*)(out + (size_t)row * DIM + lane * 4) = ov;
  float s = dx * dx + dy * dy + dzz * dzz + dw * dw;
#pragma unroll
  for (int o = 32; o > 0; o >>= 1) s += __shfl_down(s, o);
  if (lane == 0) ls[wid] = s;
  __syncthreads();
  if (threadIdx.x == 0) lossp[blockIdx.x] = ls[0] + ls[1] + ls[2] + ls[3];
  if (lane == 0) out[(size_t)OUT_QUANT + 1 + (size_t)row * K_CODES + idx] = 1.0f;
}

__global__ __launch_bounds__(256) void loss_final(const float* __restrict__ lossp,
                                                  float* __restrict__ out) {
  __shared__ float sm[256];
  float v = 0.f;
  for (int i = threadIdx.x; i < 8192; i += 256) v += lossp[i];
  sm[threadIdx.x] = v;
  __syncthreads();
  for (int s = 128; s > 0; s >>= 1) {
    if (threadIdx.x < s) sm[threadIdx.x] += sm[threadIdx.x + s];
    __syncthreads();
  }
  if (threadIdx.x == 0) out[OUT_QUANT] = sm[0] * (1.25f / 8388608.0f);
}

extern "C" void kernel_launch(void* const* d_in, const int* in_sizes, int n_in,
                              void* d_out, int out_size, void* d_ws, size_t ws_size,
                              hipStream_t stream) {
  const float* z = (const float*)d_in[0];
  const float* cb = (const float*)d_in[1];
  float* out = (float*)d_out;

  // workspace layout: keys u64[32768] | rownorm f32[32768] | codenorm f32[1024] | lossp f32[8192]
  unsigned long long* keys = (unsigned long long*)d_ws;
  float* rn = (float*)((char*)d_ws + (size_t)N_ROWS * 8);
  float* cn = rn + N_ROWS;
  float* lossp = cn + K_CODES;

  // zero loss + encodings region (d_out is poisoned before every launch)
  hipMemsetAsync(out + OUT_QUANT, 0, (size_t)(1 + (size_t)N_ROWS * K_CODES) * sizeof(float), stream);
  hipMemsetAsync(keys, 0xFF, (size_t)N_ROWS * 8, stream);

  row_norms<<<N_ROWS / 256, 256, 0, stream>>>(z, rn);
  code_norms<<<K_CODES / 256, 256, 0, stream>>>(cb, cn);
  gemm_argmin<<<2048, 256, 0, stream>>>(z, cb, rn, cn, keys);
  quantize_out<<<N_ROWS / 4, 256, 0, stream>>>(z, cb, keys, out, lossp);
  loss_final<<<1, 256, 0, stream>>>(lossp, out);
}